// Round 2
// baseline (774.395 us; speedup 1.0000x reference)
//
#include <hip/hip_runtime.h>

#define LEN 4096
#define FRAME 1024
#define DCH 128
#define NFR 4

// top-4 insert: val desc, idx asc tiebreak (matches jax.lax.top_k stability)
#define TOPK_INSERT(vv, bb)                                                     \
    {                                                                           \
        float v_ = (vv); int b_ = (bb);                                         \
        bool c0 = (v_ > tv0) || (v_ == tv0 && b_ < ti0);                        \
        bool c1 = (v_ > tv1) || (v_ == tv1 && b_ < ti1);                        \
        bool c2 = (v_ > tv2) || (v_ == tv2 && b_ < ti2);                        \
        bool c3 = (v_ > tv3) || (v_ == tv3 && b_ < ti3);                        \
        tv3 = c3 ? (c2 ? tv2 : v_) : tv3; ti3 = c3 ? (c2 ? ti2 : b_) : ti3;     \
        tv2 = c2 ? (c1 ? tv1 : v_) : tv2; ti2 = c2 ? (c1 ? ti1 : b_) : ti2;     \
        tv1 = c1 ? (c0 ? tv0 : v_) : tv1; ti1 = c1 ? (c0 ? ti0 : b_) : ti1;     \
        tv0 = c0 ? v_ : tv0;              ti0 = c0 ? b_ : ti0;                  \
    }

// ---------------------------------------------------------------------------
// Kernel 1: fused S-GEMM (S = Q_tq * V_tk^T) + 9-point band-sum + running
// top-4.  grid 512 = n(2)*tq(4)*tk(4)*ab(8)*bhalf(2), block 512.
// Each WG: 128 a-rows (S rows A0-32..A0+159) x 16 b-rows of one half
// (9 slabs of 2 b-rows, 1 overlap slab for the boundary corr row).
// corr window lives in registers (4 slots x 8 wb per thread, static idx).
// LDS 67KB -> 2 blocks/CU.
// ---------------------------------------------------------------------------
__global__ __launch_bounds__(512, 4) void corr_topk_kernel(
    const float* __restrict__ query,
    const float* __restrict__ value,
    float2* __restrict__ cand)
{
    __shared__ __align__(16) float Ssl[192 * 65];   // 49,920 B
    __shared__ __align__(16) float Qc[16 * 196];    // 12,544 B (k-major, 16B-aligned rows)
    __shared__ __align__(16) float Vc[16 * 66];     //  4,224 B

    // XCD-chunked swizzle: 64 consecutive logical WGs per XCD share Q frame
    const int hw = blockIdx.x;
    const int wg = (hw & 7) * 64 + (hw >> 3);

    const int bh = wg & 1;
    const int ab = (wg >> 1) & 7;
    const int tk = (wg >> 4) & 3;
    const int tq = (wg >> 6) & 3;
    const int n  = wg >> 8;
    const int A0 = ab * 128;

    const float* __restrict__ Qf = query + (size_t)((n * NFR + tq) * FRAME) * DCH;
    const float* __restrict__ Vf = value + (size_t)((n * NFR + tk) * FRAME) * DCH;

    const int tid = threadIdx.x;
    const int rg  = tid & 15;     // GEMM rows rg*12..rg*12+11
    const int cg  = tid >> 4;     // GEMM cols cg*2, cg*2+1
    const int a_loc = tid >> 2;   // topk: a = A0 + a_loc
    const int wq    = tid & 3;    // wb octet: wb = wq*8+u
    const int wa = a_loc & 31;
    const int ha = (A0 + a_loc) >> 5;
    const int hb_lo = bh * 16, hb_hi = bh * 16 + 16;
    const int p0 = bh ? 7 : 0;

    float cr[32];
    #pragma unroll
    for (int i = 0; i < 32; ++i) cr[i] = 0.0f;

    float tv0 = -3.402823466e38f, tv1 = tv0, tv2 = tv0, tv3 = tv0;
    int   ti0 = 0x7fffffff, ti1 = ti0, ti2 = ti0, ti3 = ti0;

#define ACC_TERM(SLOT, HP, DI) do {                                             \
    if ((unsigned)(ha + (DI)) < 32u) {                                          \
        const float* Sr = &Ssl[(a_loc + 32 + (DI) * 32) * 65 + (HP) * 32 + wq * 8]; \
        _Pragma("unroll")                                                       \
        for (int u = 0; u < 8; ++u) {                                           \
            float s = Sr[u];                                                    \
            if ((wa > 0)  && ((u > 0) || (wq > 0))) s += Sr[u - 66];            \
            if ((wa < 31) && ((u < 7) || (wq < 3))) s += Sr[u + 66];            \
            cr[(SLOT) * 8 + u] += s;                                            \
        }                                                                       \
    }                                                                           \
} while (0)

#define FINALIZE_ROW(HB, SLOT) do {                                             \
    const int hbg_ = (HB);                                                      \
    if (hbg_ >= hb_lo && hbg_ < hb_hi) {                                        \
        _Pragma("unroll")                                                       \
        for (int u = 0; u < 8; ++u) {                                           \
            TOPK_INSERT(cr[(SLOT) * 8 + u], hbg_ * 32 + wq * 8 + u);            \
            cr[(SLOT) * 8 + u] = 0.0f;                                          \
        }                                                                       \
    }                                                                           \
} while (0)

    for (int ps = 0; ps < 9; ++ps) {
        const int p = p0 + ps;

        // ---------- GEMM: 192 x 64 slab, K=128 in 8 chunks of 16
        float acc[24];
        #pragma unroll
        for (int i = 0; i < 24; ++i) acc[i] = 0.0f;

        for (int kc = 0; kc < 8; ++kc) {
            __syncthreads();
            #pragma unroll
            for (int s = 0; s < 2; ++s) {
                int i = s * 512 + tid;
                if (i < 768) {
                    int row = i >> 2, k4 = (i & 3) * 4;
                    int agl = A0 - 32 + row;
                    float4 q4 = make_float4(0.f, 0.f, 0.f, 0.f);
                    if ((unsigned)agl < (unsigned)FRAME)
                        q4 = *reinterpret_cast<const float4*>(Qf + (size_t)agl * DCH + kc * 16 + k4);
                    Qc[(k4 + 0) * 196 + row] = q4.x;
                    Qc[(k4 + 1) * 196 + row] = q4.y;
                    Qc[(k4 + 2) * 196 + row] = q4.z;
                    Qc[(k4 + 3) * 196 + row] = q4.w;
                } else {
                    int vi = i - 768;
                    int row = vi >> 2, k4 = (vi & 3) * 4;
                    float4 v4 = *reinterpret_cast<const float4*>(Vf + (size_t)(p * 64 + row) * DCH + kc * 16 + k4);
                    Vc[(k4 + 0) * 66 + row] = v4.x;
                    Vc[(k4 + 1) * 66 + row] = v4.y;
                    Vc[(k4 + 2) * 66 + row] = v4.z;
                    Vc[(k4 + 3) * 66 + row] = v4.w;
                }
            }
            __syncthreads();

            float pacc[24];
            #pragma unroll
            for (int i = 0; i < 24; ++i) pacc[i] = 0.0f;

            #pragma unroll
            for (int k = 0; k < 16; ++k) {
                const float* qr = &Qc[k * 196 + rg * 12];
                float4 q0 = *reinterpret_cast<const float4*>(qr);
                float4 q1 = *reinterpret_cast<const float4*>(qr + 4);
                float4 q2 = *reinterpret_cast<const float4*>(qr + 8);
                float2 vv = *reinterpret_cast<const float2*>(&Vc[k * 66 + cg * 2]);
                float qv[12];
                qv[0] = q0.x; qv[1] = q0.y; qv[2]  = q0.z; qv[3]  = q0.w;
                qv[4] = q1.x; qv[5] = q1.y; qv[6]  = q1.z; qv[7]  = q1.w;
                qv[8] = q2.x; qv[9] = q2.y; qv[10] = q2.z; qv[11] = q2.w;
                #pragma unroll
                for (int i = 0; i < 12; ++i) {
                    pacc[2 * i + 0] = fmaf(qv[i], vv.x, pacc[2 * i + 0]);
                    pacc[2 * i + 1] = fmaf(qv[i], vv.y, pacc[2 * i + 1]);
                }
            }
            #pragma unroll
            for (int i = 0; i < 24; ++i) acc[i] += pacc[i];   // chunked partials: rounding
        }
        __syncthreads();
        #pragma unroll
        for (int i = 0; i < 12; ++i) {
            Ssl[(rg * 12 + i) * 65 + cg * 2 + 0] = acc[2 * i + 0];
            Ssl[(rg * 12 + i) * 65 + cg * 2 + 1] = acc[2 * i + 1];
        }
        __syncthreads();

        // ---------- band-sum accumulate (window rows 2p-1 .. 2p+2), static slots
        const int hb0 = 2 * p - 1;
        if (p & 1) {
            if (hb0     >= hb_lo && hb0     < hb_hi) { ACC_TERM(1, 0, +1); }
            if (hb0 + 1 >= hb_lo && hb0 + 1 < hb_hi) { ACC_TERM(2, 0,  0); ACC_TERM(2, 1, +1); }
            if (hb0 + 2 >= hb_lo && hb0 + 2 < hb_hi) { ACC_TERM(3, 0, -1); ACC_TERM(3, 1,  0); }
            if (hb0 + 3 >= hb_lo && hb0 + 3 < hb_hi) { ACC_TERM(0, 1, -1); }
        } else {
            if (hb0     >= hb_lo && hb0     < hb_hi) { ACC_TERM(3, 0, +1); }
            if (hb0 + 1 >= hb_lo && hb0 + 1 < hb_hi) { ACC_TERM(0, 0,  0); ACC_TERM(0, 1, +1); }
            if (hb0 + 2 >= hb_lo && hb0 + 2 < hb_hi) { ACC_TERM(1, 0, -1); ACC_TERM(1, 1,  0); }
            if (hb0 + 3 >= hb_lo && hb0 + 3 < hb_hi) { ACC_TERM(2, 1, -1); }
        }

        // ---------- finalize complete rows 2p-1, 2p
        if (p & 1) { FINALIZE_ROW(2 * p - 1, 1); FINALIZE_ROW(2 * p, 2); }
        else       { FINALIZE_ROW(2 * p - 1, 3); FINALIZE_ROW(2 * p, 0); }
    }
    // last row of half 1 (hb=31, slot 3)
    if (bh) { FINALIZE_ROW(31, 3); }

    // ---------- merge top-4 across the 4 wq lanes (same wave, adjacent lanes)
    #pragma unroll
    for (int m = 1; m <= 2; m <<= 1) {
        float ov0 = __shfl_xor(tv0, m); int oi0 = __shfl_xor(ti0, m);
        float ov1 = __shfl_xor(tv1, m); int oi1 = __shfl_xor(ti1, m);
        float ov2 = __shfl_xor(tv2, m); int oi2 = __shfl_xor(ti2, m);
        float ov3 = __shfl_xor(tv3, m); int oi3 = __shfl_xor(ti3, m);
        TOPK_INSERT(ov0, oi0);
        TOPK_INSERT(ov1, oi1);
        TOPK_INSERT(ov2, oi2);
        TOPK_INSERT(ov3, oi3);
    }

    if (wq == 0) {
        const int q = tq * FRAME + A0 + a_loc;
        float2* c = cand + ((((size_t)n * LEN + q) * NFR + tk) * 2 + bh) * 4;
        c[0] = make_float2(tv0, __int_as_float(ti0));
        c[1] = make_float2(tv1, __int_as_float(ti1));
        c[2] = make_float2(tv2, __int_as_float(ti2));
        c[3] = make_float2(tv3, __int_as_float(ti3));
    }
#undef ACC_TERM
#undef FINALIZE_ROW
}

// ---------------------------------------------------------------------------
// Kernel 1b: merge the two b-halves' top-4 candidates -> final top-4 indices.
// ---------------------------------------------------------------------------
__global__ void merge_kernel(const float2* __restrict__ cand, int* __restrict__ idxb)
{
    int gid = blockIdx.x * 256 + threadIdx.x;     // 2*LEN*NFR = 32768
    const float2* c = cand + (size_t)gid * 8;
    float tv0 = -3.402823466e38f, tv1 = tv0, tv2 = tv0, tv3 = tv0;
    int   ti0 = 0x7fffffff, ti1 = ti0, ti2 = ti0, ti3 = ti0;
    #pragma unroll
    for (int r = 0; r < 8; ++r) {
        float2 e = c[r];
        TOPK_INSERT(e.x, __float_as_int(e.y));
    }
    int* o = idxb + (size_t)gid * 4;
    o[0] = ti0; o[1] = ti1; o[2] = ti2; o[3] = ti3;
}

// ---------------------------------------------------------------------------
// Kernel 2: W_out transpose.
// ---------------------------------------------------------------------------
__global__ void wt_kernel(const float* __restrict__ W, float* __restrict__ WT)
{
    int i = blockIdx.x * 256 + threadIdx.x;   // 16384
    int c = i >> 7, dd = i & 127;
    WT[c * 128 + dd] = W[dd * 128 + c];
}

// ---------------------------------------------------------------------------
// Kernel 3: sampling_locations.
// ---------------------------------------------------------------------------
__global__ void sloc_kernel(const int* __restrict__ idxb, float* __restrict__ slout)
{
    int gid = blockIdx.x * 256 + threadIdx.x;     // < 1179648
    int pp = gid & 3;
    int t1 = gid >> 2;
    int j  = t1 % 9;
    int t2 = t1 / 9;
    int t  = t2 & 3;
    int q  = (t2 >> 2) & 4095;
    int n  = t2 >> 14;
    int sel = idxb[((n * LEN + q) * NFR + t) * 4 + pp];
    int shift = (j / 3 - 1) * 32 + (j % 3 - 1);
    int r = sel + shift;
    r = r < 0 ? 0 : (r > 961 ? 961 : r);
    float2 loc = make_float2((float)(r >> 5) * (1.0f / 32.0f),
                             (float)(r & 31) * (1.0f / 32.0f));
    *reinterpret_cast<float2*>(slout + (size_t)gid * 2) = loc;
}

// ---------------------------------------------------------------------------
// Kernel 4: gather + bilinear (weights exactly 0.25) + fused projection.
// Interior fast path: 3x3 shifts x 2x2 taps collapse to a 4x4 stencil with
// [1,2,2,1] (x) [1,2,2,1] counts. Branch is block-uniform (sel shared).
// ---------------------------------------------------------------------------
__global__ __launch_bounds__(128) void gather_proj_kernel(
    const float* __restrict__ value, const int* __restrict__ idxb,
    const float* __restrict__ Wmat, int wt_transposed,
    const float* __restrict__ bout, float* __restrict__ outp)
{
    __shared__ float o[128];
    const int hw = blockIdx.x;
    const int blk = (hw & 7) * 1024 + (hw >> 3);   // XCD-chunked: each XCD one n-range
    const int n = blk >> 12;
    const int q = blk & 4095;
    const int d = threadIdx.x;

    const float CNT[4] = {1.0f, 2.0f, 2.0f, 1.0f};

    float acc = 0.0f;
    const int* ib = idxb + (size_t)(n * LEN + q) * 16;
    for (int t = 0; t < 4; ++t) {
        const float* __restrict__ Vf = value + (size_t)((n * NFR + t) * FRAME) * DCH;
        for (int pp = 0; pp < 4; ++pp) {
            int sel = ib[t * 4 + pp];
            int oh_s = sel & 31, ow_s = sel >> 5;
            if (oh_s >= 2 && oh_s <= 29 && ow_s >= 2 && ow_s <= 28) {
                const float* base = Vf + (size_t)((oh_s - 2) * 32 + (ow_s - 2)) * DCH + d;
                #pragma unroll
                for (int dyy = 0; dyy < 4; ++dyy)
                    #pragma unroll
                    for (int dxx = 0; dxx < 4; ++dxx)
                        acc = fmaf(CNT[dyy] * CNT[dxx] * 0.25f,
                                   base[(size_t)(dyy * 32 + dxx) * DCH], acc);
            } else {
                #pragma unroll
                for (int j = 0; j < 9; ++j) {
                    const int shift = (j / 3 - 1) * 32 + (j % 3 - 1);
                    int r = sel + shift;
                    r = r < 0 ? 0 : (r > 961 ? 961 : r);
                    int ow = r >> 5, oh = r & 31;
                    #pragma unroll
                    for (int dy = 0; dy < 2; ++dy)
                        #pragma unroll
                        for (int dx = 0; dx < 2; ++dx) {
                            int yi = oh - 1 + dy, xi = ow - 1 + dx;
                            if (yi >= 0 && xi >= 0)   // upper bounds always hold
                                acc += 0.25f * Vf[(size_t)(yi * 32 + xi) * DCH + d];
                        }
                }
            }
        }
    }
    o[d] = acc * (1.0f / 144.0f);   // aw = 1/(NL*P9); bilinear 0.25 folded above
    __syncthreads();
    float res = bout[d];
    if (wt_transposed) {
        #pragma unroll 8
        for (int c = 0; c < 128; ++c) res = fmaf(o[c], Wmat[c * 128 + d], res);
    } else {
        #pragma unroll 8
        for (int c = 0; c < 128; ++c) res = fmaf(o[c], Wmat[d * 128 + c], res);
    }
    outp[(size_t)(n * LEN + q) * DCH + d] = res;
}

// ---------------------------------------------------------------------------
extern "C" void kernel_launch(void* const* d_in, const int* in_sizes, int n_in,
                              void* d_out, int out_size, void* d_ws, size_t ws_size,
                              hipStream_t stream)
{
    const float* query = (const float*)d_in[0];
    const float* value = (const float*)d_in[2];
    const float* W_out = (const float*)d_in[5];
    const float* b_out = (const float*)d_in[6];

    const size_t cand_bytes = (size_t)2 * LEN * NFR * 2 * 4 * sizeof(float2); // 2 MB
    const size_t idx_bytes  = (size_t)2 * LEN * NFR * 4 * sizeof(int);        // 512 KB

    float2* cand = (float2*)d_ws;
    int*    idxb = (int*)((char*)d_ws + cand_bytes);
    float*  WT   = (float*)((char*)d_ws + cand_bytes + idx_bytes);
    const bool have_wt = ws_size >= cand_bytes + idx_bytes + (size_t)128 * 128 * sizeof(float);

    float* outp  = (float*)d_out;                               // (2,4096,128)
    float* slout = (float*)d_out + (size_t)2 * LEN * DCH;       // (2,4096,1,4,36,2)

    if (have_wt)
        hipLaunchKernelGGL(wt_kernel, dim3(64), dim3(256), 0, stream, W_out, WT);

    hipLaunchKernelGGL(corr_topk_kernel, dim3(512), dim3(512), 0, stream,
                       query, value, cand);

    hipLaunchKernelGGL(merge_kernel, dim3(128), dim3(256), 0, stream, cand, idxb);

    hipLaunchKernelGGL(sloc_kernel, dim3(4608), dim3(256), 0, stream, idxb, slout);

    hipLaunchKernelGGL(gather_proj_kernel, dim3(2 * LEN), dim3(128), 0, stream,
                       value, idxb,
                       have_wt ? WT : W_out, have_wt ? 1 : 0,
                       b_out, outp);
}